// Round 19
// baseline (190.965 us; speedup 1.0000x reference)
//
#include <hip/hip_runtime.h>
#include <hip/hip_bf16.h>
#include <math.h>

#define NTOK 4096
#define DIM 2048
#define NHEAD 1002
#define HB_STRIDE 1008       // bf16 head row stride (16B-aligned)
#define NCAT 1664
#define C0LO 1000
#define C0HI 10000
#define OSZ0 9000
#define OSZ1 40257
#define P0 9024              // W20b padded rows (141 x 64)
#define P1 40320             // W21b padded rows (630 x 64)
#define PAD0 24.0f           // pad cols cluster0: each contributes exp(0)=1
#define PAD1 63.0f
#define H0S 512
#define H1S 128
#define JS0 32               // tail0: 1024 blocks, 24.5KB, (256,4) [R16: 53us]
#define JS1 32               // tail1: 1024 blocks, 33KB, (256,4) -> 4/CU (need ~112 <= 128)
#define HEADBLKS 8
#define NT0 141              // 64-col j-tiles
#define NT1 630              // 64-col j-tiles
#define PROJB 416
#define CVTB 352

typedef __attribute__((ext_vector_type(4))) short short4v;
typedef __attribute__((ext_vector_type(8))) short short8v;
typedef __attribute__((ext_vector_type(4))) float f32x4;
typedef __hip_bfloat16 bf16;

#define GLOBAL_AS __attribute__((address_space(1)))
#define LDS_AS __attribute__((address_space(3)))

#define RAW_BAR() __builtin_amdgcn_s_barrier()
#define SCHED_FENCE() __builtin_amdgcn_sched_barrier(0)
#define WAIT_VM(N) asm volatile("s_waitcnt vmcnt(" #N ")" ::: "memory")
#define WAIT_LGKM0() asm volatile("s_waitcnt lgkmcnt(0)" ::: "memory")
#define PRIO(N) __builtin_amdgcn_s_setprio(N)

// k-interleave permutation within each 32-elem chunk (verified R9).
__device__ __forceinline__ int kperm(int c) {
  return (c & ~31) | (((c & 15) >> 2) << 3) | (((c >> 4) & 1) << 2) | (c & 3);
}

__device__ __forceinline__ void cvt8(const float* s1, const float* s2, bf16* dst) {
  union { short8v v; bf16 h[8]; } u;
  float4 a = *reinterpret_cast<const float4*>(s1);
  float4 b = *reinterpret_cast<const float4*>(s2);
  u.h[0] = __float2bfloat16(a.x); u.h[1] = __float2bfloat16(a.y);
  u.h[2] = __float2bfloat16(a.z); u.h[3] = __float2bfloat16(a.w);
  u.h[4] = __float2bfloat16(b.x); u.h[5] = __float2bfloat16(b.y);
  u.h[6] = __float2bfloat16(b.z); u.h[7] = __float2bfloat16(b.w);
  *reinterpret_cast<short8v*>(dst) = u.v;
}

__device__ __forceinline__ void zero8(bf16* dst) {
  union { short8v v; bf16 h[8]; } u;
#pragma unroll
  for (int e = 0; e < 8; ++e) u.h[e] = __float2bfloat16(0.f);
  *reinterpret_cast<short8v*>(dst) = u.v;
}

// ---------- cvt for xb + Wcat (proj inputs) ----------
__global__ __launch_bounds__(256) void cvt_xw(
    const float* __restrict__ x, const float* __restrict__ W_head,
    const float* __restrict__ W1_0, const float* __restrict__ W1_1,
    bf16* __restrict__ xb, bf16* __restrict__ Wcat) {
  const long NX = (long)NTOK * DIM / 8;
  const long NC = (long)NCAT * DIM / 8;
  long gid = (long)blockIdx.x * 256 + threadIdx.x;
  if (gid < NX) {
    long rel = gid * 8;
    long c1 = (rel & ~31L) + ((rel >> 3) & 3) * 4;
    cvt8(x + c1, x + c1 + 16, xb + rel);
  } else if (gid < NX + NC) {
    long rel = (gid - NX) * 8;
    int row = (int)(rel >> 11);
    long c1 = (rel & ~31L) + ((rel >> 3) & 3) * 4;
    int col = (int)(c1 & 2047);
    const float* srow = nullptr;
    if (row < NHEAD) srow = W_head + (long)row * DIM;
    else if (row < 1024) srow = nullptr;             // zero padding rows
    else if (row < 1536) srow = W1_0 + (long)(row - 1024) * DIM;
    else srow = W1_1 + (long)(row - 1536) * DIM;
    if (srow) cvt8(srow + col, srow + col + 16, Wcat + rel);
    else      zero8(Wcat + rel);
  }
}

// ---------- staging helpers (16B granules, XOR swizzle; padded: no clamps) ----------
__device__ __forceinline__ void stage_tile(const bf16* __restrict__ g, int row0,
                                           int ld, int k0,
                                           char* lds, int wave, int lane) {
#pragma unroll
  for (int c = 0; c < 4; ++c) {
    int rbase = wave * 32 + c * 8;
    int row = rbase + (lane >> 3);
    int slot = (lane & 7) ^ (row & 7);
    const bf16* src = g + (size_t)(row0 + row) * ld + k0 + slot * 8;
    __builtin_amdgcn_global_load_lds((const GLOBAL_AS unsigned int*)src,
                                     (LDS_AS unsigned int*)(lds + rbase * 128),
                                     16, 0, 0);
  }
}

__device__ __forceinline__ void stage_tileB64(const bf16* __restrict__ g, int row0,
                                              int ld, int k0,
                                              char* lds, int wave, int lane) {
#pragma unroll
  for (int c = 0; c < 2; ++c) {
    int rbase = wave * 16 + c * 8;
    int row = rbase + (lane >> 3);
    int slot = (lane & 7) ^ (row & 7);
    const bf16* src = g + (size_t)(row0 + row) * ld + k0 + slot * 8;
    __builtin_amdgcn_global_load_lds((const GLOBAL_AS unsigned int*)src,
                                     (LDS_AS unsigned int*)(lds + rbase * 128),
                                     16, 0, 0);
  }
}

__device__ __forceinline__ void stage_tile256(const bf16* __restrict__ g, int row0,
                                              int ld, char* lds, int wave, int lane) {
#pragma unroll
  for (int c = 0; c < 8; ++c) {
    int rbase = wave * 32 + c * 4;
    int row = rbase + (lane >> 4);
    int slot = (lane & 15) ^ (row & 7);
    const bf16* src = g + (size_t)(row0 + row) * ld + slot * 8;
    __builtin_amdgcn_global_load_lds((const GLOBAL_AS unsigned int*)src,
                                     (LDS_AS unsigned int*)(lds + rbase * 256),
                                     16, 0, 0);
  }
}

__device__ __forceinline__ void stage_tile256_64(const bf16* __restrict__ g, int row0,
                                                 int ld, char* lds, int wave, int lane) {
#pragma unroll
  for (int c = 0; c < 4; ++c) {
    int rbase = wave * 16 + c * 4;
    int row = rbase + (lane >> 4);
    int slot = (lane & 15) ^ (row & 7);
    const bf16* src = g + (size_t)(row0 + row) * ld + slot * 8;
    __builtin_amdgcn_global_load_lds((const GLOBAL_AS unsigned int*)src,
                                     (LDS_AS unsigned int*)(lds + rbase * 256),
                                     16, 0, 0);
  }
}

__device__ __forceinline__ short8v read_frag(const char* lds, int row, int kk, int lane) {
  int slot = (kk * 4 + (lane >> 4)) ^ (row & 7);
  return *reinterpret_cast<const short8v*>(lds + row * 128 + slot * 16);
}
__device__ __forceinline__ short8v read_frag256(const char* lds, int row, int kk, int lane) {
  int slot = (kk * 4 + (lane >> 4)) ^ (row & 7);
  return *reinterpret_cast<const short8v*>(lds + row * 256 + slot * 16);
}

__device__ __forceinline__ void reduce_write_ps(float srun[4][4], float* reds,
                                                float* ps, int slice, int tok0,
                                                int lane, int wr, int wc) {
#pragma unroll
  for (int off = 1; off < 16; off <<= 1)
#pragma unroll
    for (int m = 0; m < 4; ++m)
#pragma unroll
      for (int r = 0; r < 4; ++r) srun[m][r] += __shfl_xor(srun[m][r], off);
  __syncthreads();
  if (wc == 0 && (lane & 15) == 0) {
#pragma unroll
    for (int m = 0; m < 4; ++m)
#pragma unroll
      for (int r = 0; r < 4; ++r)
        reds[wr * 64 + m * 16 + (lane >> 4) * 4 + r] = srun[m][r];
  }
  __syncthreads();
  if (wc == 1 && (lane & 15) == 0) {
#pragma unroll
    for (int m = 0; m < 4; ++m)
#pragma unroll
      for (int r = 0; r < 4; ++r) {
        int row = wr * 64 + m * 16 + (lane >> 4) * 4 + r;
        ps[(size_t)slice * NTOK + tok0 + row] = reds[row] + srun[m][r];
      }
  }
}

// ---------- tail0 (H=512): BM128 x BN64, 2-barrier, 24.5KB, (256,4) [R16] ----------
__global__ __launch_bounds__(256, 4) void tail0_lse(
    const bf16* __restrict__ Ab, const bf16* __restrict__ W2b,
    float* __restrict__ ps) {
  __shared__ __align__(16) char As[16384];
  __shared__ __align__(16) char Bs[8192];
  __shared__ float reds[128];
  int tid = threadIdx.x;
  int lane = tid & 63, wave = tid >> 6;
  int wr = wave >> 1, wc = wave & 1;
  int tok0 = blockIdx.x * 128;
  int ys = blockIdx.y;
  int t_lo = (NT0 * ys) / JS0, t_hi = (NT0 * (ys + 1)) / JS0;
  float srun[4][4] = {};
  for (int jt = t_lo; jt < t_hi; ++jt) {
    int j0 = jt * 64;
    f32x4 acc[4][2] = {};
    for (int k0 = 0; k0 < H0S; k0 += 64) {
      __syncthreads();
      stage_tile(Ab, tok0, H0S, k0, As, wave, lane);
      stage_tileB64(W2b, j0, H0S, k0, Bs, wave, lane);
      __syncthreads();
      PRIO(1);
#pragma unroll
      for (int kk = 0; kk < 2; ++kk) {
        short8v af[4], bfr[2];
#pragma unroll
        for (int m = 0; m < 4; ++m)
          af[m] = read_frag(As, wr * 64 + m * 16 + (lane & 15), kk, lane);
#pragma unroll
        for (int n = 0; n < 2; ++n)
          bfr[n] = read_frag(Bs, wc * 32 + n * 16 + (lane & 15), kk, lane);
#pragma unroll
        for (int m = 0; m < 4; ++m)
#pragma unroll
          for (int n = 0; n < 2; ++n)
            acc[m][n] = __builtin_amdgcn_mfma_f32_16x16x32_bf16(af[m], bfr[n], acc[m][n], 0, 0, 0);
      }
      PRIO(0);
    }
#pragma unroll
    for (int m = 0; m < 4; ++m)
#pragma unroll
      for (int n = 0; n < 2; ++n)
#pragma unroll
        for (int r = 0; r < 4; ++r) srun[m][r] += __expf(acc[m][n][r]);
  }
  reduce_write_ps(srun, reds, ps, ys, tok0, lane, wr, wc);
}

// ---------- tail1 (H=128): A-in-regs, BN=64 dbuf, 33KB, (256,4) ----------
// Unified reg need ~112 (R13 measurement of same body) <= 128 budget @4/EU.
__device__ void tail1_body(const bf16* __restrict__ Ab, const bf16* __restrict__ W2b,
                           float* __restrict__ ps, char* lds) {
  char* buf0 = lds;             // 16 KB
  char* buf1 = lds + 16384;     // 16 KB
  float* reds = (float*)(lds + 32768);
  int tid = threadIdx.x;
  int lane = tid & 63, wave = tid >> 6;
  int wr = wave >> 1, wc = wave & 1;
  int tok0 = blockIdx.x * 128;
  int ys = blockIdx.y;
  int t_lo = (NT1 * ys) / JS1, t_hi = (NT1 * (ys + 1)) / JS1;
  int nt = t_hi - t_lo;

  stage_tile256(Ab, tok0, H1S, lds, wave, lane);
  WAIT_VM(0); SCHED_FENCE();
  RAW_BAR();
  short8v afr[4][4];
#pragma unroll
  for (int kk = 0; kk < 4; ++kk)
#pragma unroll
    for (int m = 0; m < 4; ++m)
      afr[kk][m] = read_frag256(lds, wr * 64 + m * 16 + (lane & 15), kk, lane);
  WAIT_LGKM0(); SCHED_FENCE();
  RAW_BAR();
  stage_tile256_64(W2b, t_lo * 64, H1S, buf0, wave, lane);
  if (nt > 1) stage_tile256_64(W2b, (t_lo + 1) * 64, H1S, buf1, wave, lane);

  float srun[4][4] = {};
  for (int i = 0; i < nt; ++i) {
    char* cur = (i & 1) ? buf1 : buf0;
    if (i + 1 < nt) { WAIT_VM(4); } else { WAIT_VM(0); }
    SCHED_FENCE();
    RAW_BAR();
    f32x4 acc[4][2] = {};
    PRIO(1);
#pragma unroll
    for (int kk = 0; kk < 4; ++kk) {
      short8v bfr[2];
#pragma unroll
      for (int n = 0; n < 2; ++n)
        bfr[n] = read_frag256(cur, wc * 32 + n * 16 + (lane & 15), kk, lane);
#pragma unroll
      for (int m = 0; m < 4; ++m)
#pragma unroll
        for (int n = 0; n < 2; ++n)
          acc[m][n] = __builtin_amdgcn_mfma_f32_16x16x32_bf16(afr[kk][m], bfr[n], acc[m][n], 0, 0, 0);
    }
    PRIO(0);
#pragma unroll
    for (int m = 0; m < 4; ++m)
#pragma unroll
      for (int n = 0; n < 2; ++n)
#pragma unroll
        for (int r = 0; r < 4; ++r) srun[m][r] += __expf(acc[m][n][r]);
    SCHED_FENCE();
    RAW_BAR();
    if (i + 2 < nt) stage_tile256_64(W2b, (t_lo + i + 2) * 64, H1S, cur, wave, lane);
  }
  reduce_write_ps(srun, reds, ps, ys, tok0, lane, wr, wc);
}

__global__ __launch_bounds__(256, 4) void tail1_lse(
    const bf16* __restrict__ Ab, const bf16* __restrict__ W2b,
    float* __restrict__ ps) {
  __shared__ __align__(16) char lds[33280];
  tail1_body(Ab, W2b, ps, lds);
}

// ---------- proj GEMM + riding W2 converter blocks ----------
__global__ __launch_bounds__(256, 3) void proj_plus(
    const bf16* __restrict__ A, const bf16* __restrict__ B,
    const float* __restrict__ W2_0, const float* __restrict__ W2_1,
    bf16* __restrict__ W20b, bf16* __restrict__ W21b,
    bf16* __restrict__ head_b, bf16* __restrict__ h0b, bf16* __restrict__ h1b,
    float* __restrict__ ps_head) {
  __shared__ __align__(16) char As[16384];
  __shared__ __align__(16) char Bs[16384];
  __shared__ float reds[128];
  if (blockIdx.x >= PROJB) {
    const long G20 = (long)P0 * H0S / 8;
    const long G21 = (long)P1 * H1S / 8;
    const long R20 = (long)OSZ0 * H0S / 8;
    const long R21 = (long)OSZ1 * H1S / 8;
    long idx = (long)(blockIdx.x - PROJB) * 256 + threadIdx.x;
    const long stride = (long)CVTB * 256;
    for (; idx < G20 + G21; idx += stride) {
      long rel; const float* srcb; bf16* dstb; bool real;
      if (idx < G20) { rel = idx * 8;          srcb = W2_0; dstb = W20b + rel; real = idx < R20; }
      else { long j = idx - G20; rel = j * 8;  srcb = W2_1; dstb = W21b + rel; real = j < R21; }
      if (real) {
        long c1 = (rel & ~31L) + ((rel >> 3) & 3) * 4;
        cvt8(srcb + c1, srcb + c1 + 16, dstb);
      } else {
        zero8(dstb);
      }
    }
    return;
  }
  int tid = threadIdx.x;
  int lane = tid & 63, wave = tid >> 6;
  int wr = wave >> 1, wc = wave & 1;
  int wgid = blockIdx.x;
  int cx = wgid & 7, w = wgid >> 3;
  int col_b = w >> 2;
  int row_b = cx * 4 + (w & 3);
  int row0 = row_b * 128, col0 = col_b * 128;
  f32x4 acc[4][4] = {};
  for (int k0 = 0; k0 < DIM; k0 += 64) {
    __syncthreads();
    stage_tile(A, row0, DIM, k0, As, wave, lane);
    stage_tile(B, col0, DIM, k0, Bs, wave, lane);
    __syncthreads();
#pragma unroll
    for (int kk = 0; kk < 2; ++kk) {
      short8v af[4], bfr[4];
#pragma unroll
      for (int m = 0; m < 4; ++m)
        af[m] = read_frag(As, wr * 64 + m * 16 + (lane & 15), kk, lane);
#pragma unroll
      for (int n = 0; n < 4; ++n)
        bfr[n] = read_frag(Bs, wc * 64 + n * 16 + (lane & 15), kk, lane);
#pragma unroll
      for (int m = 0; m < 4; ++m)
#pragma unroll
        for (int n = 0; n < 4; ++n)
          acc[m][n] = __builtin_amdgcn_mfma_f32_16x16x32_bf16(af[m], bfr[n], acc[m][n], 0, 0, 0);
    }
  }
  float srun[4][4] = {};
#pragma unroll
  for (int m = 0; m < 4; ++m) {
    int row = row0 + wr * 64 + m * 16 + (lane >> 4) * 4;
#pragma unroll
    for (int n = 0; n < 4; ++n) {
      int col = col0 + wc * 64 + n * 16 + (lane & 15);
#pragma unroll
      for (int r = 0; r < 4; ++r) {
        float v = acc[m][n][r];
        if (col < NHEAD) {
          head_b[(size_t)(row + r) * HB_STRIDE + col] = __float2bfloat16(v);
          srun[m][r] += __expf(v);
        } else if (col >= 1024 && col < 1536) {
          h0b[(size_t)(row + r) * H0S + kperm(col - 1024)] = __float2bfloat16(v);
        } else if (col >= 1536) {
          h1b[(size_t)(row + r) * H1S + kperm(col - 1536)] = __float2bfloat16(v);
        }
      }
    }
  }
  if (col_b < HEADBLKS) {
    reduce_write_ps(srun, reds, ps_head, col_b, row0, lane, wr, wc);
  }
}

// ---------- finalize: one wave per token; bf16 gathers; permuted-group dot ----------
__global__ __launch_bounds__(256) void finalize2(
    const int* __restrict__ target, const bf16* __restrict__ head_b,
    const float* __restrict__ ps_head,
    const bf16* __restrict__ h0b, const bf16* __restrict__ h1b,
    const float* __restrict__ W2_0, const float* __restrict__ W2_1,
    const float* __restrict__ ps0, const float* __restrict__ ps1,
    float* __restrict__ out) {
  int warp = threadIdx.x >> 6, lane = threadIdx.x & 63;
  int i = blockIdx.x * 4 + warp;
  if (i >= NTOK) return;
  int t = target[i];
  float sh = 0.f;
#pragma unroll
  for (int s = 0; s < HEADBLKS; ++s) sh += ps_head[(size_t)s * NTOK + i];
  float lse_head = logf(sh);
  float res;
  if (t < C0LO) {
    res = __bfloat162float(head_b[(size_t)i * HB_STRIDE + t]) - lse_head;
  } else {
    int c = (t < C0HI) ? 0 : 1;
    int H = c ? H1S : H0S;
    int low = c ? C0HI : C0LO;
    const bf16* hv = (c ? h1b : h0b) + (size_t)i * H;
    const float* wv = (c ? W2_1 : W2_0) + (size_t)(t - low) * H;
    float p = 0.f;
    for (int k = lane * 4; k < H; k += 256) {
      int j = (k >> 2) & 7;
      int chunk = k & ~31;
      int wk = chunk + ((j & 1) << 4) + ((j >> 1) << 2);
      ushort4 hraw = *reinterpret_cast<const ushort4*>(
          reinterpret_cast<const unsigned short*>(hv) + k);
      float4 b = *reinterpret_cast<const float4*>(wv + wk);
      union { unsigned int u; float f; } cv;
      float hx, hy, hz, hw;
      cv.u = (unsigned int)hraw.x << 16; hx = cv.f;
      cv.u = (unsigned int)hraw.y << 16; hy = cv.f;
      cv.u = (unsigned int)hraw.z << 16; hz = cv.f;
      cv.u = (unsigned int)hraw.w << 16; hw = cv.f;
      p += hx * b.x + hy * b.y + hz * b.z + hw * b.w;
    }
#pragma unroll
    for (int off = 32; off > 0; off >>= 1) p += __shfl_xor(p, off);
    const float* ps = c ? ps1 : ps0;
    int js = c ? JS1 : JS0;
    float S = 0.f;
    for (int s = 0; s < js; ++s) S += ps[(size_t)s * NTOK + i];
    S -= c ? PAD1 : PAD0;
    float cl = __bfloat162float(head_b[(size_t)i * HB_STRIDE + C0LO + c]);
    res = (cl - lse_head) + (p - logf(S));
  }
  if (lane == 0) out[i] = res;
}

__global__ __launch_bounds__(256) void loss_kernel(float* __restrict__ out) {
  __shared__ float red[256];
  int tid = threadIdx.x;
  float s = 0.f;
  for (int j = tid; j < NTOK; j += 256) s += out[j];
  red[tid] = s; __syncthreads();
  for (int off = 128; off > 0; off >>= 1) {
    if (tid < off) red[tid] += red[tid + off];
    __syncthreads();
  }
  if (tid == 0) out[NTOK] = -red[0] / (float)NTOK;
}

extern "C" void kernel_launch(void* const* d_in, const int* in_sizes, int n_in,
                              void* d_out, int out_size, void* d_ws, size_t ws_size,
                              hipStream_t stream) {
  (void)in_sizes; (void)n_in; (void)out_size; (void)ws_size;
  const float* x = (const float*)d_in[0];
  const int* target = (const int*)d_in[1];
  const float* W_head = (const float*)d_in[2];
  const float* W1_0 = (const float*)d_in[3];
  const float* W2_0 = (const float*)d_in[4];
  const float* W1_1 = (const float*)d_in[5];
  const float* W2_1 = (const float*)d_in[6];
  float* out = (float*)d_out;

  char* w = (char*)d_ws;
  size_t off = 0;
  auto alloc = [&](size_t bytes) -> void* {
    void* p = w + off;
    off = (off + bytes + 255) & ~(size_t)255;
    return p;
  };
  bf16* xb     = (bf16*)alloc((size_t)NTOK * DIM * 2);
  bf16* Wcat   = (bf16*)alloc((size_t)NCAT * DIM * 2);
  bf16* W20b   = (bf16*)alloc((size_t)P0 * H0S * 2);
  bf16* W21b   = (bf16*)alloc((size_t)P1 * H1S * 2);
  bf16* head_b = (bf16*)alloc((size_t)NTOK * HB_STRIDE * 2);
  bf16* h0b    = (bf16*)alloc((size_t)NTOK * H0S * 2);
  bf16* h1b    = (bf16*)alloc((size_t)NTOK * H1S * 2);
  float* ps_head = (float*)alloc((size_t)HEADBLKS * NTOK * 4);
  float* ps0 = (float*)alloc((size_t)JS0 * NTOK * 4);
  float* ps1 = (float*)alloc((size_t)JS1 * NTOK * 4);

  dim3 blk(256);
  const long NXW = (long)NTOK * DIM / 8 + (long)NCAT * DIM / 8;
  cvt_xw<<<dim3((unsigned)((NXW + 255) / 256)), blk, 0, stream>>>(
      x, W_head, W1_0, W1_1, xb, Wcat);

  proj_plus<<<dim3(PROJB + CVTB), blk, 0, stream>>>(
      xb, Wcat, W2_0, W2_1, W20b, W21b, head_b, h0b, h1b, ps_head);

  tail0_lse<<<dim3(NTOK / 128, JS0), blk, 0, stream>>>(h0b, W20b, ps0);
  tail1_lse<<<dim3(NTOK / 128, JS1), blk, 0, stream>>>(h1b, W21b, ps1);

  finalize2<<<dim3(NTOK / 4), blk, 0, stream>>>(target, head_b, ps_head,
                                                h0b, h1b, W2_0, W2_1,
                                                ps0, ps1, out);
  loss_kernel<<<1, blk, 0, stream>>>(out);
}

// Round 20
// 166.751 us; speedup vs baseline: 1.1452x; 1.1452x over previous
//
#include <hip/hip_runtime.h>
#include <hip/hip_bf16.h>
#include <math.h>

#define NTOK 4096
#define DIM 2048
#define NHEAD 1002
#define HB_STRIDE 1008       // bf16 head row stride (16B-aligned)
#define NCAT 1664
#define C0LO 1000
#define C0HI 10000
#define OSZ0 9000
#define OSZ1 40257
#define P0 9024              // W20b padded rows (141 x 64)
#define P1 40320             // W21b padded rows (630 x 64)
#define PAD0 24.0f           // pad cols cluster0: each contributes exp(0)=1
#define PAD1 63.0f
#define H0S 512
#define H1S 128
#define JS0 32               // tail0: 1024 blocks, 24.5KB, (256,4) [R16/R18: 53us]
#define JS1 24               // tail1: 768 blocks, 33KB, (256,3) [R18: ~50us; (256,4) spills]
#define HEADBLKS 8
#define NT0 141              // 64-col j-tiles
#define NT1 630              // 64-col j-tiles
#define PROJB 416
#define CVTB 352

typedef __attribute__((ext_vector_type(4))) short short4v;
typedef __attribute__((ext_vector_type(8))) short short8v;
typedef __attribute__((ext_vector_type(4))) float f32x4;
typedef __hip_bfloat16 bf16;

#define GLOBAL_AS __attribute__((address_space(1)))
#define LDS_AS __attribute__((address_space(3)))

#define RAW_BAR() __builtin_amdgcn_s_barrier()
#define SCHED_FENCE() __builtin_amdgcn_sched_barrier(0)
#define WAIT_VM(N) asm volatile("s_waitcnt vmcnt(" #N ")" ::: "memory")
#define WAIT_LGKM0() asm volatile("s_waitcnt lgkmcnt(0)" ::: "memory")
#define PRIO(N) __builtin_amdgcn_s_setprio(N)

// k-interleave permutation within each 32-elem chunk (verified R9).
__device__ __forceinline__ int kperm(int c) {
  return (c & ~31) | (((c & 15) >> 2) << 3) | (((c >> 4) & 1) << 2) | (c & 3);
}

__device__ __forceinline__ void cvt8(const float* s1, const float* s2, bf16* dst) {
  union { short8v v; bf16 h[8]; } u;
  float4 a = *reinterpret_cast<const float4*>(s1);
  float4 b = *reinterpret_cast<const float4*>(s2);
  u.h[0] = __float2bfloat16(a.x); u.h[1] = __float2bfloat16(a.y);
  u.h[2] = __float2bfloat16(a.z); u.h[3] = __float2bfloat16(a.w);
  u.h[4] = __float2bfloat16(b.x); u.h[5] = __float2bfloat16(b.y);
  u.h[6] = __float2bfloat16(b.z); u.h[7] = __float2bfloat16(b.w);
  *reinterpret_cast<short8v*>(dst) = u.v;
}

__device__ __forceinline__ void zero8(bf16* dst) {
  union { short8v v; bf16 h[8]; } u;
#pragma unroll
  for (int e = 0; e < 8; ++e) u.h[e] = __float2bfloat16(0.f);
  *reinterpret_cast<short8v*>(dst) = u.v;
}

// ---------- cvt for xb + Wcat (proj inputs) ----------
__global__ __launch_bounds__(256) void cvt_xw(
    const float* __restrict__ x, const float* __restrict__ W_head,
    const float* __restrict__ W1_0, const float* __restrict__ W1_1,
    bf16* __restrict__ xb, bf16* __restrict__ Wcat) {
  const long NX = (long)NTOK * DIM / 8;
  const long NC = (long)NCAT * DIM / 8;
  long gid = (long)blockIdx.x * 256 + threadIdx.x;
  if (gid < NX) {
    long rel = gid * 8;
    long c1 = (rel & ~31L) + ((rel >> 3) & 3) * 4;
    cvt8(x + c1, x + c1 + 16, xb + rel);
  } else if (gid < NX + NC) {
    long rel = (gid - NX) * 8;
    int row = (int)(rel >> 11);
    long c1 = (rel & ~31L) + ((rel >> 3) & 3) * 4;
    int col = (int)(c1 & 2047);
    const float* srow = nullptr;
    if (row < NHEAD) srow = W_head + (long)row * DIM;
    else if (row < 1024) srow = nullptr;             // zero padding rows
    else if (row < 1536) srow = W1_0 + (long)(row - 1024) * DIM;
    else srow = W1_1 + (long)(row - 1536) * DIM;
    if (srow) cvt8(srow + col, srow + col + 16, Wcat + rel);
    else      zero8(Wcat + rel);
  }
}

// ---------- staging helpers (16B granules, XOR swizzle; padded: no clamps) ----------
__device__ __forceinline__ void stage_tile(const bf16* __restrict__ g, int row0,
                                           int ld, int k0,
                                           char* lds, int wave, int lane) {
#pragma unroll
  for (int c = 0; c < 4; ++c) {
    int rbase = wave * 32 + c * 8;
    int row = rbase + (lane >> 3);
    int slot = (lane & 7) ^ (row & 7);
    const bf16* src = g + (size_t)(row0 + row) * ld + k0 + slot * 8;
    __builtin_amdgcn_global_load_lds((const GLOBAL_AS unsigned int*)src,
                                     (LDS_AS unsigned int*)(lds + rbase * 128),
                                     16, 0, 0);
  }
}

__device__ __forceinline__ void stage_tileB64(const bf16* __restrict__ g, int row0,
                                              int ld, int k0,
                                              char* lds, int wave, int lane) {
#pragma unroll
  for (int c = 0; c < 2; ++c) {
    int rbase = wave * 16 + c * 8;
    int row = rbase + (lane >> 3);
    int slot = (lane & 7) ^ (row & 7);
    const bf16* src = g + (size_t)(row0 + row) * ld + k0 + slot * 8;
    __builtin_amdgcn_global_load_lds((const GLOBAL_AS unsigned int*)src,
                                     (LDS_AS unsigned int*)(lds + rbase * 128),
                                     16, 0, 0);
  }
}

__device__ __forceinline__ void stage_tile256(const bf16* __restrict__ g, int row0,
                                              int ld, char* lds, int wave, int lane) {
#pragma unroll
  for (int c = 0; c < 8; ++c) {
    int rbase = wave * 32 + c * 4;
    int row = rbase + (lane >> 4);
    int slot = (lane & 15) ^ (row & 7);
    const bf16* src = g + (size_t)(row0 + row) * ld + slot * 8;
    __builtin_amdgcn_global_load_lds((const GLOBAL_AS unsigned int*)src,
                                     (LDS_AS unsigned int*)(lds + rbase * 256),
                                     16, 0, 0);
  }
}

__device__ __forceinline__ void stage_tile256_64(const bf16* __restrict__ g, int row0,
                                                 int ld, char* lds, int wave, int lane) {
#pragma unroll
  for (int c = 0; c < 4; ++c) {
    int rbase = wave * 16 + c * 4;
    int row = rbase + (lane >> 4);
    int slot = (lane & 15) ^ (row & 7);
    const bf16* src = g + (size_t)(row0 + row) * ld + slot * 8;
    __builtin_amdgcn_global_load_lds((const GLOBAL_AS unsigned int*)src,
                                     (LDS_AS unsigned int*)(lds + rbase * 256),
                                     16, 0, 0);
  }
}

__device__ __forceinline__ short8v read_frag(const char* lds, int row, int kk, int lane) {
  int slot = (kk * 4 + (lane >> 4)) ^ (row & 7);
  return *reinterpret_cast<const short8v*>(lds + row * 128 + slot * 16);
}
__device__ __forceinline__ short8v read_frag256(const char* lds, int row, int kk, int lane) {
  int slot = (kk * 4 + (lane >> 4)) ^ (row & 7);
  return *reinterpret_cast<const short8v*>(lds + row * 256 + slot * 16);
}

__device__ __forceinline__ void reduce_write_ps(float srun[4][4], float* reds,
                                                float* ps, int slice, int tok0,
                                                int lane, int wr, int wc) {
#pragma unroll
  for (int off = 1; off < 16; off <<= 1)
#pragma unroll
    for (int m = 0; m < 4; ++m)
#pragma unroll
      for (int r = 0; r < 4; ++r) srun[m][r] += __shfl_xor(srun[m][r], off);
  __syncthreads();
  if (wc == 0 && (lane & 15) == 0) {
#pragma unroll
    for (int m = 0; m < 4; ++m)
#pragma unroll
      for (int r = 0; r < 4; ++r)
        reds[wr * 64 + m * 16 + (lane >> 4) * 4 + r] = srun[m][r];
  }
  __syncthreads();
  if (wc == 1 && (lane & 15) == 0) {
#pragma unroll
    for (int m = 0; m < 4; ++m)
#pragma unroll
      for (int r = 0; r < 4; ++r) {
        int row = wr * 64 + m * 16 + (lane >> 4) * 4 + r;
        ps[(size_t)slice * NTOK + tok0 + row] = reds[row] + srun[m][r];
      }
  }
}

// ---------- tail0 (H=512): BM128 x BN64, 2-barrier, 24.5KB, (256,4) [R16] ----------
__global__ __launch_bounds__(256, 4) void tail0_lse(
    const bf16* __restrict__ Ab, const bf16* __restrict__ W2b,
    float* __restrict__ ps) {
  __shared__ __align__(16) char As[16384];
  __shared__ __align__(16) char Bs[8192];
  __shared__ float reds[128];
  int tid = threadIdx.x;
  int lane = tid & 63, wave = tid >> 6;
  int wr = wave >> 1, wc = wave & 1;
  int tok0 = blockIdx.x * 128;
  int ys = blockIdx.y;
  int t_lo = (NT0 * ys) / JS0, t_hi = (NT0 * (ys + 1)) / JS0;
  float srun[4][4] = {};
  for (int jt = t_lo; jt < t_hi; ++jt) {
    int j0 = jt * 64;
    f32x4 acc[4][2] = {};
    for (int k0 = 0; k0 < H0S; k0 += 64) {
      __syncthreads();
      stage_tile(Ab, tok0, H0S, k0, As, wave, lane);
      stage_tileB64(W2b, j0, H0S, k0, Bs, wave, lane);
      __syncthreads();
      PRIO(1);
#pragma unroll
      for (int kk = 0; kk < 2; ++kk) {
        short8v af[4], bfr[2];
#pragma unroll
        for (int m = 0; m < 4; ++m)
          af[m] = read_frag(As, wr * 64 + m * 16 + (lane & 15), kk, lane);
#pragma unroll
        for (int n = 0; n < 2; ++n)
          bfr[n] = read_frag(Bs, wc * 32 + n * 16 + (lane & 15), kk, lane);
#pragma unroll
        for (int m = 0; m < 4; ++m)
#pragma unroll
          for (int n = 0; n < 2; ++n)
            acc[m][n] = __builtin_amdgcn_mfma_f32_16x16x32_bf16(af[m], bfr[n], acc[m][n], 0, 0, 0);
      }
      PRIO(0);
    }
#pragma unroll
    for (int m = 0; m < 4; ++m)
#pragma unroll
      for (int n = 0; n < 2; ++n)
#pragma unroll
        for (int r = 0; r < 4; ++r) srun[m][r] += __expf(acc[m][n][r]);
  }
  reduce_write_ps(srun, reds, ps, ys, tok0, lane, wr, wc);
}

// ---------- tail1 (H=128): A-in-regs, BN=64 dbuf, 33KB, (256,3) [R18] ----------
__device__ void tail1_body(const bf16* __restrict__ Ab, const bf16* __restrict__ W2b,
                           float* __restrict__ ps, char* lds) {
  char* buf0 = lds;             // 16 KB
  char* buf1 = lds + 16384;     // 16 KB
  float* reds = (float*)(lds + 32768);
  int tid = threadIdx.x;
  int lane = tid & 63, wave = tid >> 6;
  int wr = wave >> 1, wc = wave & 1;
  int tok0 = blockIdx.x * 128;
  int ys = blockIdx.y;
  int t_lo = (NT1 * ys) / JS1, t_hi = (NT1 * (ys + 1)) / JS1;
  int nt = t_hi - t_lo;

  stage_tile256(Ab, tok0, H1S, lds, wave, lane);
  WAIT_VM(0); SCHED_FENCE();
  RAW_BAR();
  short8v afr[4][4];
#pragma unroll
  for (int kk = 0; kk < 4; ++kk)
#pragma unroll
    for (int m = 0; m < 4; ++m)
      afr[kk][m] = read_frag256(lds, wr * 64 + m * 16 + (lane & 15), kk, lane);
  WAIT_LGKM0(); SCHED_FENCE();
  RAW_BAR();
  stage_tile256_64(W2b, t_lo * 64, H1S, buf0, wave, lane);
  if (nt > 1) stage_tile256_64(W2b, (t_lo + 1) * 64, H1S, buf1, wave, lane);

  float srun[4][4] = {};
  for (int i = 0; i < nt; ++i) {
    char* cur = (i & 1) ? buf1 : buf0;
    if (i + 1 < nt) { WAIT_VM(4); } else { WAIT_VM(0); }
    SCHED_FENCE();
    RAW_BAR();
    f32x4 acc[4][2] = {};
    PRIO(1);
#pragma unroll
    for (int kk = 0; kk < 4; ++kk) {
      short8v bfr[2];
#pragma unroll
      for (int n = 0; n < 2; ++n)
        bfr[n] = read_frag256(cur, wc * 32 + n * 16 + (lane & 15), kk, lane);
#pragma unroll
      for (int m = 0; m < 4; ++m)
#pragma unroll
        for (int n = 0; n < 2; ++n)
          acc[m][n] = __builtin_amdgcn_mfma_f32_16x16x32_bf16(afr[kk][m], bfr[n], acc[m][n], 0, 0, 0);
    }
    PRIO(0);
#pragma unroll
    for (int m = 0; m < 4; ++m)
#pragma unroll
      for (int n = 0; n < 2; ++n)
#pragma unroll
        for (int r = 0; r < 4; ++r) srun[m][r] += __expf(acc[m][n][r]);
    SCHED_FENCE();
    RAW_BAR();
    if (i + 2 < nt) stage_tile256_64(W2b, (t_lo + i + 2) * 64, H1S, cur, wave, lane);
  }
  reduce_write_ps(srun, reds, ps, ys, tok0, lane, wr, wc);
}

__global__ __launch_bounds__(256, 3) void tail1_lse(
    const bf16* __restrict__ Ab, const bf16* __restrict__ W2b,
    float* __restrict__ ps) {
  __shared__ __align__(16) char lds[33280];
  tail1_body(Ab, W2b, ps, lds);
}

// ---------- proj GEMM + riding W2 converter blocks ----------
__global__ __launch_bounds__(256, 3) void proj_plus(
    const bf16* __restrict__ A, const bf16* __restrict__ B,
    const float* __restrict__ W2_0, const float* __restrict__ W2_1,
    bf16* __restrict__ W20b, bf16* __restrict__ W21b,
    bf16* __restrict__ head_b, bf16* __restrict__ h0b, bf16* __restrict__ h1b,
    float* __restrict__ ps_head) {
  __shared__ __align__(16) char As[16384];
  __shared__ __align__(16) char Bs[16384];
  __shared__ float reds[128];
  if (blockIdx.x >= PROJB) {
    const long G20 = (long)P0 * H0S / 8;
    const long G21 = (long)P1 * H1S / 8;
    const long R20 = (long)OSZ0 * H0S / 8;
    const long R21 = (long)OSZ1 * H1S / 8;
    long idx = (long)(blockIdx.x - PROJB) * 256 + threadIdx.x;
    const long stride = (long)CVTB * 256;
    for (; idx < G20 + G21; idx += stride) {
      long rel; const float* srcb; bf16* dstb; bool real;
      if (idx < G20) { rel = idx * 8;          srcb = W2_0; dstb = W20b + rel; real = idx < R20; }
      else { long j = idx - G20; rel = j * 8;  srcb = W2_1; dstb = W21b + rel; real = j < R21; }
      if (real) {
        long c1 = (rel & ~31L) + ((rel >> 3) & 3) * 4;
        cvt8(srcb + c1, srcb + c1 + 16, dstb);
      } else {
        zero8(dstb);
      }
    }
    return;
  }
  int tid = threadIdx.x;
  int lane = tid & 63, wave = tid >> 6;
  int wr = wave >> 1, wc = wave & 1;
  int wgid = blockIdx.x;
  int cx = wgid & 7, w = wgid >> 3;
  int col_b = w >> 2;
  int row_b = cx * 4 + (w & 3);
  int row0 = row_b * 128, col0 = col_b * 128;
  f32x4 acc[4][4] = {};
  for (int k0 = 0; k0 < DIM; k0 += 64) {
    __syncthreads();
    stage_tile(A, row0, DIM, k0, As, wave, lane);
    stage_tile(B, col0, DIM, k0, Bs, wave, lane);
    __syncthreads();
#pragma unroll
    for (int kk = 0; kk < 2; ++kk) {
      short8v af[4], bfr[4];
#pragma unroll
      for (int m = 0; m < 4; ++m)
        af[m] = read_frag(As, wr * 64 + m * 16 + (lane & 15), kk, lane);
#pragma unroll
      for (int n = 0; n < 4; ++n)
        bfr[n] = read_frag(Bs, wc * 64 + n * 16 + (lane & 15), kk, lane);
#pragma unroll
      for (int m = 0; m < 4; ++m)
#pragma unroll
        for (int n = 0; n < 4; ++n)
          acc[m][n] = __builtin_amdgcn_mfma_f32_16x16x32_bf16(af[m], bfr[n], acc[m][n], 0, 0, 0);
    }
  }
  float srun[4][4] = {};
#pragma unroll
  for (int m = 0; m < 4; ++m) {
    int row = row0 + wr * 64 + m * 16 + (lane >> 4) * 4;
#pragma unroll
    for (int n = 0; n < 4; ++n) {
      int col = col0 + wc * 64 + n * 16 + (lane & 15);
#pragma unroll
      for (int r = 0; r < 4; ++r) {
        float v = acc[m][n][r];
        if (col < NHEAD) {
          head_b[(size_t)(row + r) * HB_STRIDE + col] = __float2bfloat16(v);
          srun[m][r] += __expf(v);
        } else if (col >= 1024 && col < 1536) {
          h0b[(size_t)(row + r) * H0S + kperm(col - 1024)] = __float2bfloat16(v);
        } else if (col >= 1536) {
          h1b[(size_t)(row + r) * H1S + kperm(col - 1536)] = __float2bfloat16(v);
        }
      }
    }
  }
  if (col_b < HEADBLKS) {
    reduce_write_ps(srun, reds, ps_head, col_b, row0, lane, wr, wc);
  }
}

// ---------- finalize: one wave per token; bf16 gathers; permuted-group dot ----------
__global__ __launch_bounds__(256) void finalize2(
    const int* __restrict__ target, const bf16* __restrict__ head_b,
    const float* __restrict__ ps_head,
    const bf16* __restrict__ h0b, const bf16* __restrict__ h1b,
    const float* __restrict__ W2_0, const float* __restrict__ W2_1,
    const float* __restrict__ ps0, const float* __restrict__ ps1,
    float* __restrict__ out) {
  int warp = threadIdx.x >> 6, lane = threadIdx.x & 63;
  int i = blockIdx.x * 4 + warp;
  if (i >= NTOK) return;
  int t = target[i];
  float sh = 0.f;
#pragma unroll
  for (int s = 0; s < HEADBLKS; ++s) sh += ps_head[(size_t)s * NTOK + i];
  float lse_head = logf(sh);
  float res;
  if (t < C0LO) {
    res = __bfloat162float(head_b[(size_t)i * HB_STRIDE + t]) - lse_head;
  } else {
    int c = (t < C0HI) ? 0 : 1;
    int H = c ? H1S : H0S;
    int low = c ? C0HI : C0LO;
    const bf16* hv = (c ? h1b : h0b) + (size_t)i * H;
    const float* wv = (c ? W2_1 : W2_0) + (size_t)(t - low) * H;
    float p = 0.f;
    for (int k = lane * 4; k < H; k += 256) {
      int j = (k >> 2) & 7;
      int chunk = k & ~31;
      int wk = chunk + ((j & 1) << 4) + ((j >> 1) << 2);
      ushort4 hraw = *reinterpret_cast<const ushort4*>(
          reinterpret_cast<const unsigned short*>(hv) + k);
      float4 b = *reinterpret_cast<const float4*>(wv + wk);
      union { unsigned int u; float f; } cv;
      float hx, hy, hz, hw;
      cv.u = (unsigned int)hraw.x << 16; hx = cv.f;
      cv.u = (unsigned int)hraw.y << 16; hy = cv.f;
      cv.u = (unsigned int)hraw.z << 16; hz = cv.f;
      cv.u = (unsigned int)hraw.w << 16; hw = cv.f;
      p += hx * b.x + hy * b.y + hz * b.z + hw * b.w;
    }
#pragma unroll
    for (int off = 32; off > 0; off >>= 1) p += __shfl_xor(p, off);
    const float* ps = c ? ps1 : ps0;
    int js = c ? JS1 : JS0;
    float S = 0.f;
    for (int s = 0; s < js; ++s) S += ps[(size_t)s * NTOK + i];
    S -= c ? PAD1 : PAD0;
    float cl = __bfloat162float(head_b[(size_t)i * HB_STRIDE + C0LO + c]);
    res = (cl - lse_head) + (p - logf(S));
  }
  if (lane == 0) out[i] = res;
}

__global__ __launch_bounds__(256) void loss_kernel(float* __restrict__ out) {
  __shared__ float red[256];
  int tid = threadIdx.x;
  float s = 0.f;
  for (int j = tid; j < NTOK; j += 256) s += out[j];
  red[tid] = s; __syncthreads();
  for (int off = 128; off > 0; off >>= 1) {
    if (tid < off) red[tid] += red[tid + off];
    __syncthreads();
  }
  if (tid == 0) out[NTOK] = -red[0] / (float)NTOK;
}

extern "C" void kernel_launch(void* const* d_in, const int* in_sizes, int n_in,
                              void* d_out, int out_size, void* d_ws, size_t ws_size,
                              hipStream_t stream) {
  (void)in_sizes; (void)n_in; (void)out_size; (void)ws_size;
  const float* x = (const float*)d_in[0];
  const int* target = (const int*)d_in[1];
  const float* W_head = (const float*)d_in[2];
  const float* W1_0 = (const float*)d_in[3];
  const float* W2_0 = (const float*)d_in[4];
  const float* W1_1 = (const float*)d_in[5];
  const float* W2_1 = (const float*)d_in[6];
  float* out = (float*)d_out;

  char* w = (char*)d_ws;
  size_t off = 0;
  auto alloc = [&](size_t bytes) -> void* {
    void* p = w + off;
    off = (off + bytes + 255) & ~(size_t)255;
    return p;
  };
  bf16* xb     = (bf16*)alloc((size_t)NTOK * DIM * 2);
  bf16* Wcat   = (bf16*)alloc((size_t)NCAT * DIM * 2);
  bf16* W20b   = (bf16*)alloc((size_t)P0 * H0S * 2);
  bf16* W21b   = (bf16*)alloc((size_t)P1 * H1S * 2);
  bf16* head_b = (bf16*)alloc((size_t)NTOK * HB_STRIDE * 2);
  bf16* h0b    = (bf16*)alloc((size_t)NTOK * H0S * 2);
  bf16* h1b    = (bf16*)alloc((size_t)NTOK * H1S * 2);
  float* ps_head = (float*)alloc((size_t)HEADBLKS * NTOK * 4);
  float* ps0 = (float*)alloc((size_t)JS0 * NTOK * 4);
  float* ps1 = (float*)alloc((size_t)JS1 * NTOK * 4);

  dim3 blk(256);
  const long NXW = (long)NTOK * DIM / 8 + (long)NCAT * DIM / 8;
  cvt_xw<<<dim3((unsigned)((NXW + 255) / 256)), blk, 0, stream>>>(
      x, W_head, W1_0, W1_1, xb, Wcat);

  proj_plus<<<dim3(PROJB + CVTB), blk, 0, stream>>>(
      xb, Wcat, W2_0, W2_1, W20b, W21b, head_b, h0b, h1b, ps_head);

  tail0_lse<<<dim3(NTOK / 128, JS0), blk, 0, stream>>>(h0b, W20b, ps0);
  tail1_lse<<<dim3(NTOK / 128, JS1), blk, 0, stream>>>(h1b, W21b, ps1);

  finalize2<<<dim3(NTOK / 4), blk, 0, stream>>>(target, head_b, ps_head,
                                                h0b, h1b, W2_0, W2_1,
                                                ps0, ps1, out);
  loss_kernel<<<1, blk, 0, stream>>>(out);
}